// Round 7
// baseline (744.112 us; speedup 1.0000x reference)
//
#include <hip/hip_runtime.h>
#include <stdint.h>

#define CDIM   256
#define KCODES 1024
#define HWSZ   4096
#define NROWS  131072
// packed-key screen: flag threshold on 10-bit-truncated gap.
// original verified DELTA=4e-4; truncation of top-2 biased values < 1.22e-4
// (biased values provably in (0.25,1.25)), so 4.7e-4 keeps guaranteed-flag band >= 4e-4.
#define DELTA_P 4.7e-4f

// workspace layout (bytes)
#define WS_BQ    0          // 4 KB   fp32 Bq[k]
#define WS_IDX   4096       // 512 KB int   idx[n]
#define WS_CBBF  528384     // 512 KB bf16  cbbf[k][c]
#define WS_CNT   1052672    // 4 B (padded 128) flagged count
#define WS_LIST  1052800    // 512 KB int flagged row list
#define WS_SLOT  1577216    // 1 MB   u64 per-flag argmin slots
#define WS_AS    2625792    // 512 KB fp32 A[j] sum-sq per flagged row
#define WS_XC    3150080    // compact fp32 x rows for flagged list (capn * 1KB, ws_size-guarded)

typedef __attribute__((ext_vector_type(8))) short short8;
typedef __attribute__((ext_vector_type(4))) float f32x4;

__device__ inline unsigned short bf16rne(float f) {
    uint32_t u = __float_as_uint(f);
    u += 0x7FFF + ((u >> 16) & 1);
    return (unsigned short)(u >> 16);
}

__device__ __forceinline__ unsigned umin32(unsigned a, unsigned b) { return a < b ? a : b; }
__device__ __forceinline__ unsigned umax32(unsigned a, unsigned b) { return a > b ? a : b; }

// monotone float->u32 map; min-u64 over (mapped_s, k) == "lowest s, tie -> lowest k"
// == numpy argmin-first semantics. Order-independent, deterministic.
__device__ __forceinline__ unsigned long long packkey(float s, int k) {
    unsigned b = __float_as_uint(s);
    unsigned m = (b & 0x80000000u) ? ~b : (b | 0x80000000u);
    return ((unsigned long long)m << 32) | (unsigned)k;
}

// ---------- Bq[k] = np.sum(cb_row^2), numpy pairwise tree (verified r2) ----------
__global__ void codesq_kernel(const float* __restrict__ cb, float* __restrict__ Bq) {
#pragma clang fp contract(off)
    int k = blockIdx.x * 256 + threadIdx.x;
    if (k >= KCODES) return;
    const float* er = cb + (size_t)k * CDIM;
    float half_s[2];
    for (int h = 0; h < 2; ++h) {
        float r[8];
        #pragma unroll
        for (int j = 0; j < 8; ++j) { float v = er[h*128 + j]; r[j] = v * v; }
        for (int i = 8; i < 128; i += 8) {
            #pragma unroll
            for (int j = 0; j < 8; ++j) { float v = er[h*128 + i + j]; float sq = v*v; r[j] = r[j] + sq; }
        }
        half_s[h] = ((r[0]+r[1]) + (r[2]+r[3])) + ((r[4]+r[5]) + (r[6]+r[7]));
    }
    Bq[k] = half_s[0] + half_s[1];
}

// ---------- cb fp32 -> bf16 (+ zero flag counter) ----------
__global__ void cbcvt_kernel(const float* __restrict__ cb, unsigned short* __restrict__ cbbf,
                             int* __restrict__ counter) {
    int i = blockIdx.x * 256 + threadIdx.x;      // 65536 float4 groups
    float4 v = ((const float4*)cb)[i];
    ushort4 o;
    o.x = bf16rne(v.x); o.y = bf16rne(v.y); o.z = bf16rne(v.z); o.w = bf16rne(v.w);
    ((ushort4*)cbbf)[i] = o;
    if (i == 0) *counter = 0;
}

// ---------- MFMA bf16 screen: per-row top2 of (|e|^2 - 2 x.e) ----------
// r7 change: __launch_bounds__(256, 2) -> (256, 4). r6 counters showed 2 blocks/CU
// (Occupancy 21.9%) with MfmaUtil 16% / VALUBusy 19% / hbm 5.5% -- latency-bound,
// no pipe saturated. LDS 35.8KB x4 = 143KB <= 160KB and VGPR 112 <= 128, so 4
// blocks/CU fit; request 4 waves/EU for 2x TLP.
__global__ __launch_bounds__(256, 4)
void screen_kernel(const float* __restrict__ x, const unsigned short* __restrict__ cbbf,
                   const float* __restrict__ Bq,
                   int* __restrict__ idx_out, float* __restrict__ outF,
                   int* __restrict__ flag_list, int* __restrict__ counter,
                   unsigned long long* __restrict__ slots) {
    __shared__ unsigned short xs[64 * 264];      // [row][c], pad 256->264 (A operand)
    __shared__ unsigned int sRed[4][64][2];

    const int t = threadIdx.x;
    const int w = t >> 6, l = t & 63;
    const int l15 = l & 15, quad = l >> 4;
    const int r0 = blockIdx.x * 64;
    const float* xbase = x + (size_t)(r0 >> 12) * (CDIM * HWSZ) + (r0 & 4095);

    // ---- stage x tile: fp32 [c][row] global -> bf16 [row][c] LDS (once) ----
    {
        int cbase = (t >> 4) * 2;
        int row4  = (t & 15) * 4;
        for (int it = 0; it < 8; ++it) {
            int c = cbase + it * 32;
            float4 fa = *(const float4*)(xbase + (size_t)c * HWSZ + row4);
            float4 fb = *(const float4*)(xbase + (size_t)(c + 1) * HWSZ + row4);
            *(uint32_t*)&xs[(row4+0)*264 + c] = (uint32_t)bf16rne(fa.x) | ((uint32_t)bf16rne(fb.x) << 16);
            *(uint32_t*)&xs[(row4+1)*264 + c] = (uint32_t)bf16rne(fa.y) | ((uint32_t)bf16rne(fb.y) << 16);
            *(uint32_t*)&xs[(row4+2)*264 + c] = (uint32_t)bf16rne(fa.z) | ((uint32_t)bf16rne(fb.z) << 16);
            *(uint32_t*)&xs[(row4+3)*264 + c] = (uint32_t)bf16rne(fa.w) | ((uint32_t)bf16rne(fb.w) << 16);
        }
    }

    __syncthreads();

    // ---- A fragments (compiler chooses regs vs LDS re-read under the 128-VGPR cap) ----
    short8 af[8][4];
    #pragma unroll
    for (int step = 0; step < 8; ++step)
        #pragma unroll
        for (int rf = 0; rf < 4; ++rf)
            af[step][rf] = *(const short8*)&xs[(rf*16 + l15)*264 + step*32 + quad*8];

    const unsigned short* bbase = cbbf + (size_t)(w*32 + l15) * CDIM + quad * 8;
    const int kbase = w*32 + l15;

    unsigned int K1[16], K2[16];
    #pragma unroll
    for (int i = 0; i < 16; ++i) { K1[i] = 0xFFFFFFFFu; K2[i] = 0xFFFFFFFFu; }

    for (int kt = 0; kt < 8; ++kt) {
        float bqp0 = Bq[kt*128 + kbase]      + 0.75f;
        float bqp1 = Bq[kt*128 + kbase + 16] + 0.75f;

        f32x4 acc[4][2];
        #pragma unroll
        for (int rf = 0; rf < 4; ++rf)
            #pragma unroll
            for (int cf = 0; cf < 2; ++cf) acc[rf][cf] = (f32x4){0.f, 0.f, 0.f, 0.f};

        #pragma unroll
        for (int step = 0; step < 8; ++step) {    // k-chunk of 32: c = step*32 + quad*8 + j
            int koff = step * 32;
            short8 bfr0 = *(const short8*)(bbase + (size_t)(kt*128)      * CDIM + koff);
            short8 bfr1 = *(const short8*)(bbase + (size_t)(kt*128 + 16) * CDIM + koff);
            #pragma unroll
            for (int rf = 0; rf < 4; ++rf) {
                acc[rf][0] = __builtin_amdgcn_mfma_f32_16x16x32_bf16(af[step][rf], bfr0, acc[rf][0], 0, 0, 0);
                acc[rf][1] = __builtin_amdgcn_mfma_f32_16x16x32_bf16(af[step][rf], bfr1, acc[rf][1], 0, 0, 0);
            }
        }

        unsigned int kk0 = (unsigned)(kt*128 + kbase);
        unsigned int kk1 = kk0 + 16u;
        #pragma unroll
        for (int rf = 0; rf < 4; ++rf)
            #pragma unroll
            for (int reg = 0; reg < 4; ++reg) {
                int st = rf*4 + reg;
                {
                    float s = fmaf(-2.f, acc[rf][0][reg], bqp0);
                    unsigned int key = (__float_as_uint(s) & 0xFFFFFC00u) | kk0;
                    unsigned int t1 = umin32(key, K1[st]);
                    unsigned int t2 = umax32(key, K1[st]);
                    K1[st] = t1;
                    K2[st] = umin32(t2, K2[st]);
                }
                {
                    float s = fmaf(-2.f, acc[rf][1][reg], bqp1);
                    unsigned int key = (__float_as_uint(s) & 0xFFFFFC00u) | kk1;
                    unsigned int t1 = umin32(key, K1[st]);
                    unsigned int t2 = umax32(key, K1[st]);
                    K1[st] = t1;
                    K2[st] = umin32(t2, K2[st]);
                }
            }
    }

    #pragma unroll
    for (int st = 0; st < 16; ++st) {
        #pragma unroll
        for (int m = 1; m < 16; m <<= 1) {
            unsigned int o1 = (unsigned int)__shfl_xor((int)K1[st], m, 64);
            unsigned int o2 = (unsigned int)__shfl_xor((int)K2[st], m, 64);
            unsigned int n2 = umin32(umax32(K1[st], o1), umin32(K2[st], o2));
            K1[st] = umin32(K1[st], o1);
            K2[st] = n2;
        }
    }
    if (l15 == 0) {
        #pragma unroll
        for (int rf = 0; rf < 4; ++rf)
            #pragma unroll
            for (int reg = 0; reg < 4; ++reg) {
                int r = rf*16 + quad*4 + reg;
                int st = rf*4 + reg;
                sRed[w][r][0] = K1[st];
                sRed[w][r][1] = K2[st];
            }
    }
    __syncthreads();
    if (t < 64) {
        unsigned int A1 = sRed[0][t][0], A2 = sRed[0][t][1];
        #pragma unroll
        for (int ww = 1; ww < 4; ++ww) {
            unsigned int B1 = sRed[ww][t][0], B2 = sRed[ww][t][1];
            unsigned int n2 = umin32(umax32(A1, B1), umin32(A2, B2));
            A1 = umin32(A1, B1);
            A2 = n2;
        }
        int row = r0 + t;
        int k1i = (int)(A1 & 1023u);
        idx_out[row] = k1i;
        outF[row] = (float)k1i;
        float v1 = __uint_as_float(A1 & 0xFFFFFC00u);
        float v2 = __uint_as_float(A2 & 0xFFFFFC00u);
        if (!(v2 - v1 > DELTA_P)) {               // NaN-safe: garbage -> flagged -> exact path
            int pos = atomicAdd(counter, 1);
            flag_list[pos] = row;
            slots[pos] = 0xFFFFFFFFFFFFFFFFull;   // init argmin slot for rescore
        }
    }
}

// ---------- xcopy: gather flagged rows' exact fp32 x into compact [flag][256] ----------
__global__ __launch_bounds__(256)
void xcopy_kernel(const float* __restrict__ x, const int* __restrict__ flag_list,
                  const int* __restrict__ counter, float* __restrict__ xc, int capn) {
    int cnt = *counter; if (cnt > capn) cnt = capn;
    for (int base = blockIdx.x * 64; base < cnt; base += gridDim.x * 64) {
        int j = base + (threadIdx.x >> 2);
        if (j < cnt) {
            int row = flag_list[j];
            const float* xr = x + (size_t)(row >> 12) * (CDIM * HWSZ) + (row & 4095);
            int c0 = (threadIdx.x & 3) * 64;
            float* dst = xc + (size_t)j * CDIM + c0;
            #pragma unroll 8
            for (int c = 0; c < 64; ++c)
                dst[c] = xr[(size_t)(c0 + c) * HWSZ];
        }
    }
}

// ---------- A[j] = np.sum(x_row^2) for flagged rows, verified numpy pairwise tree ----------
// Reads the exact-copy xc values (or scattered x beyond capn) -> bit-identical to the
// in-rescore sA computation it replaces.
__global__ void asq_kernel(const float* __restrict__ x, const float* __restrict__ xc,
                           const int* __restrict__ flag_list, const int* __restrict__ counter,
                           float* __restrict__ As, int capn) {
#pragma clang fp contract(off)
    int cnt = *counter;
    int jf = blockIdx.x * 256 + threadIdx.x;
    if (jf >= cnt) return;
    const float* src;
    size_t stride;
    if (jf < capn) { src = xc + (size_t)jf * CDIM; stride = 1; }
    else {
        int row = flag_list[jf];
        src = x + (size_t)(row >> 12) * (CDIM * HWSZ) + (row & 4095);
        stride = HWSZ;
    }
    float half_s[2];
    for (int h = 0; h < 2; ++h) {
        float r[8];
        #pragma unroll
        for (int j = 0; j < 8; ++j) { float v = src[(size_t)(h*128 + j) * stride]; r[j] = v * v; }
        for (int i = 8; i < 128; i += 8) {
            #pragma unroll
            for (int j = 0; j < 8; ++j) { float v = src[(size_t)(h*128 + i + j) * stride]; float sq = v*v; r[j] = r[j] + sq; }
        }
        half_s[h] = ((r[0]+r[1]) + (r[2]+r[3])) + ((r[4]+r[5]) + (r[6]+r[7]));
    }
    As[jf] = half_s[0] + half_s[1];
}

// ---------- exact np-fp32 rescore, v5 (unchanged -- out of top-5 at r6) ----------
// Per (row,code): single fp32 fmaf chain c=0..255 ascending; T1=A+Bq; s=T1-2*acc.
__global__ __launch_bounds__(256, 2)
void rescore_kernel(const float* __restrict__ x, const float* __restrict__ cb,
                    const float* __restrict__ Bq,
                    const int* __restrict__ flag_list, const int* __restrict__ counter,
                    const float* __restrict__ xc, const float* __restrict__ As, int capn,
                    unsigned long long* __restrict__ slots) {
    __shared__ float cbs[64 * 256];     // 64 codes, chunk-swizzled: lc -> lc^(code&7)

    int cnt = *counter;
    if (cnt <= 0) return;
    int nbat  = (cnt + 63) >> 6;
    int nwork = nbat << 4;
    for (int wk = blockIdx.x; wk < nwork; wk += gridDim.x) {
        int bat = wk >> 4;
        int kt0 = (wk & 15) << 6;       // this unit's 64-code tile base
        __syncthreads();
        // stage 64 codes coalesced, chunk-swizzled
        {
            int kc = threadIdx.x >> 2, seg = threadIdx.x & 3;
            const float* crow = cb + (size_t)(kt0 + kc) * CDIM + seg * 64;
            float* dst = &cbs[kc * 256];
            int kw = kc & 7;
            #pragma unroll
            for (int i2 = 0; i2 < 16; ++i2) {
                int lc = seg*16 + i2;
                *(float4*)&dst[(lc ^ kw) << 2] = *(const float4*)&crow[i2 << 2];
            }
        }
        __syncthreads();

        const int rq = threadIdx.x >> 4;      // row quad: flag idx j0+0..3
        const int cq = threadIdx.x & 15;      // code lane: codes cq + 16*j, j=0..3
        const int sw = cq & 7;
        const int j0 = bat * 64 + rq * 4;

        int jc[4]; float Ar[4];
        #pragma unroll
        for (int i = 0; i < 4; ++i) {
            int jj = j0 + i;
            jc[i] = (jj < cnt) ? jj : (cnt - 1);
            Ar[i] = As[jc[i]];
        }
        float bq[4]; const float* eb[4];
        #pragma unroll
        for (int j = 0; j < 4; ++j) {
            bq[j] = Bq[kt0 + cq + j*16];
            eb[j] = &cbs[(cq + j*16) * 256];
        }

        float acc[4][4];
        #pragma unroll
        for (int i = 0; i < 4; ++i)
            #pragma unroll
            for (int j = 0; j < 4; ++j) acc[i][j] = 0.f;

        if (jc[3] < capn) {
            // fast path: xv from compact xc (exact copies -> identical chain values)
            const float* xb[4];
            #pragma unroll
            for (int i = 0; i < 4; ++i) xb[i] = xc + (size_t)jc[i] * CDIM;
            #pragma unroll 2
            for (int c4 = 0; c4 < 64; ++c4) {
                float4 ev[4], xv[4];
                #pragma unroll
                for (int j = 0; j < 4; ++j) ev[j] = *(const float4*)&eb[j][(c4 ^ sw) << 2];
                #pragma unroll
                for (int i = 0; i < 4; ++i) xv[i] = *(const float4*)&xb[i][c4 << 2];
                #pragma unroll
                for (int i = 0; i < 4; ++i)
                    #pragma unroll
                    for (int j = 0; j < 4; ++j) {
                        float a = acc[i][j];
                        a = fmaf(xv[i].x, ev[j].x, a);
                        a = fmaf(xv[i].y, ev[j].y, a);
                        a = fmaf(xv[i].z, ev[j].z, a);
                        a = fmaf(xv[i].w, ev[j].w, a);
                        acc[i][j] = a;
                    }
            }
        } else {
            // fallback (workspace too small): xv gathered from x, same chain order
            const float* xb[4];
            #pragma unroll
            for (int i = 0; i < 4; ++i) {
                int row = flag_list[jc[i]];
                xb[i] = x + (size_t)(row >> 12) * (CDIM * HWSZ) + (row & 4095);
            }
            for (int c4 = 0; c4 < 64; ++c4) {
                float4 ev[4], xv[4];
                #pragma unroll
                for (int j = 0; j < 4; ++j) ev[j] = *(const float4*)&eb[j][(c4 ^ sw) << 2];
                #pragma unroll
                for (int i = 0; i < 4; ++i) {
                    xv[i].x = xb[i][(size_t)(c4*4 + 0) * HWSZ];
                    xv[i].y = xb[i][(size_t)(c4*4 + 1) * HWSZ];
                    xv[i].z = xb[i][(size_t)(c4*4 + 2) * HWSZ];
                    xv[i].w = xb[i][(size_t)(c4*4 + 3) * HWSZ];
                }
                #pragma unroll
                for (int i = 0; i < 4; ++i)
                    #pragma unroll
                    for (int j = 0; j < 4; ++j) {
                        float a = acc[i][j];
                        a = fmaf(xv[i].x, ev[j].x, a);
                        a = fmaf(xv[i].y, ev[j].y, a);
                        a = fmaf(xv[i].z, ev[j].z, a);
                        a = fmaf(xv[i].w, ev[j].w, a);
                        acc[i][j] = a;
                    }
            }
        }

        // finish: T1 = A + Bq; s = T1 - 2*acc  (identical ops; k ascending in j)
        float bv[4]; int bk[4];
        #pragma unroll
        for (int i = 0; i < 4; ++i) { bv[i] = 3.4e38f; bk[i] = 0; }
        #pragma unroll
        for (int j = 0; j < 4; ++j) {
            int k = kt0 + cq + j*16;
            #pragma unroll
            for (int i = 0; i < 4; ++i) {
                float T1 = Ar[i] + bq[j];
                float s  = T1 - 2.0f * acc[i][j];
                if (s < bv[i]) { bv[i] = s; bk[i] = k; }
            }
        }
        // reduce across the 16 code-lanes of each row group, then one atomicMin per row
        #pragma unroll
        for (int i = 0; i < 4; ++i) {
            float b = bv[i]; int k = bk[i];
            #pragma unroll
            for (int m = 1; m < 16; m <<= 1) {
                float ov = __shfl_xor(b, m, 64);
                int   ok = __shfl_xor(k, m, 64);
                if (ov < b || (ov == b && ok < k)) { b = ov; k = ok; }
            }
            bv[i] = b; bk[i] = k;
        }
        if (cq == 0) {
            #pragma unroll
            for (int i = 0; i < 4; ++i) {
                int jj = j0 + i;
                if (jj < cnt) atomicMin(&slots[jj], packkey(bv[i], bk[i]));
            }
        }
    }
}

// ---------- fixup: slots -> idx/outF for flagged rows ----------
__global__ void fixup_kernel(const unsigned long long* __restrict__ slots,
                             const int* __restrict__ flag_list,
                             const int* __restrict__ counter,
                             int* __restrict__ idx_out, float* __restrict__ outF) {
    int cnt = *counter;
    int t = blockIdx.x * 256 + threadIdx.x;
    if (t >= cnt) return;
    int row = flag_list[t];
    int k = (int)(unsigned)(slots[t] & 0xFFFFFFFFull);
    idx_out[row] = k;
    outF[row] = (float)k;
}

// ---------- gather codebook rows + NHWC->NCHW transpose (verified r2, unchanged) ----------
__global__ __launch_bounds__(256)
void gather_kernel(const float* __restrict__ cb, const int* __restrict__ idx,
                   float* __restrict__ out) {
    __shared__ int   sIdx[64];
    __shared__ float tile[64 * 129];
    const int t  = threadIdx.x;
    const int bh = blockIdx.x;
    const int b  = bh >> 6, h = bh & 63;

    if (t < 64) {
        int id = idx[bh * 64 + t];
        sIdx[t] = id;
        out[bh * 64 + t] = (float)id;
    }
    __syncthreads();

    float* qout = out + NROWS + (size_t)b * (CDIM * HWSZ) + h * 64;

    for (int c0 = 0; c0 < CDIM; c0 += 128) {
        if (c0) __syncthreads();
        {
            int ww = t >> 2, seg = t & 3;
            const float* crow = cb + (size_t)sIdx[ww] * CDIM + c0;
            #pragma unroll
            for (int jj = 0; jj < 8; ++jj) {
                int f = seg + 4 * jj;
                float4 v = *(const float4*)(crow + 4 * f);
                float* dst = &tile[ww * 129 + 4 * f];
                dst[0] = v.x; dst[1] = v.y; dst[2] = v.z; dst[3] = v.w;
            }
        }
        __syncthreads();
        {
            int g = t >> 4, w4 = (t & 15) * 4;
            #pragma unroll
            for (int it = 0; it < 8; ++it) {
                int cl = it * 16 + g;
                float4 v;
                v.x = tile[(w4 + 0) * 129 + cl];
                v.y = tile[(w4 + 1) * 129 + cl];
                v.z = tile[(w4 + 2) * 129 + cl];
                v.w = tile[(w4 + 3) * 129 + cl];
                *(float4*)(qout + (size_t)(c0 + cl) * HWSZ + w4) = v;
            }
        }
    }
}

extern "C" void kernel_launch(void* const* d_in, const int* in_sizes, int n_in,
                              void* d_out, int out_size, void* d_ws, size_t ws_size,
                              hipStream_t stream) {
    const float* x  = (const float*)d_in[0];
    const float* cb = (const float*)d_in[1];
    char* ws = (char*)d_ws;
    float*              Bq    = (float*)(ws + WS_BQ);
    int*                idxbf = (int*)(ws + WS_IDX);
    unsigned short*     cbbf  = (unsigned short*)(ws + WS_CBBF);
    int*                cnt   = (int*)(ws + WS_CNT);
    int*                list  = (int*)(ws + WS_LIST);
    unsigned long long* slots = (unsigned long long*)(ws + WS_SLOT);
    float*              As    = (float*)(ws + WS_AS);
    float*              xc    = (float*)(ws + WS_XC);
    float*              out   = (float*)d_out;

    // compact-x capacity from whatever workspace we actually got (runtime-guarded)
    int capn = 0;
    if (ws_size > (size_t)WS_XC) {
        size_t avail = (ws_size - (size_t)WS_XC) / (CDIM * sizeof(float));
        capn = (avail > (size_t)NROWS) ? NROWS : (int)avail;
    }

    codesq_kernel<<<KCODES / 256, 256, 0, stream>>>(cb, Bq);
    cbcvt_kernel <<<256, 256, 0, stream>>>(cb, cbbf, cnt);
    screen_kernel<<<NROWS / 64, 256, 0, stream>>>(x, cbbf, Bq, idxbf, out, list, cnt, slots);
    if (capn > 0)
        xcopy_kernel<<<2048, 256, 0, stream>>>(x, list, cnt, xc, capn);
    asq_kernel   <<<NROWS / 256, 256, 0, stream>>>(x, xc, list, cnt, As, capn);
    rescore_kernel<<<2048, 256, 0, stream>>>(x, cb, Bq, list, cnt, xc, As, capn, slots);
    fixup_kernel <<<NROWS / 256, 256, 0, stream>>>(slots, list, cnt, idxbf, out);
    gather_kernel<<<32 * 64, 256, 0, stream>>>(cb, idxbf, out);
}

// Round 8
// 540.402 us; speedup vs baseline: 1.3770x; 1.3770x over previous
//
#include <hip/hip_runtime.h>
#include <stdint.h>

#define CDIM   256
#define KCODES 1024
#define HWSZ   4096
#define NROWS  131072
// packed-key screen: flag threshold on 10-bit-truncated gap.
// original verified DELTA=4e-4; truncation of top-2 biased values < 1.22e-4
// (biased values provably in (0.25,1.25)), so 4.7e-4 keeps guaranteed-flag band >= 4e-4.
#define DELTA_P 4.7e-4f

// workspace layout (bytes)
#define WS_BQ    0          // 4 KB   fp32 Bq[k]
#define WS_IDX   4096       // 512 KB int   idx[n]
#define WS_CBBF  528384     // 512 KB bf16  cbbf[k][c]
#define WS_CNT   1052672    // 4 B (padded 128) flagged count
#define WS_LIST  1052800    // 512 KB int flagged row list
#define WS_SLOT  1577216    // 1 MB   u64 per-flag argmin slots
#define WS_AS    2625792    // 512 KB fp32 A[j] sum-sq per flagged row
#define WS_XC    3150080    // compact fp32 x rows for flagged list (capn * 1KB, ws_size-guarded)

typedef __attribute__((ext_vector_type(8))) short short8;
typedef __attribute__((ext_vector_type(4))) float f32x4;

__device__ inline unsigned short bf16rne(float f) {
    uint32_t u = __float_as_uint(f);
    u += 0x7FFF + ((u >> 16) & 1);
    return (unsigned short)(u >> 16);
}

__device__ __forceinline__ unsigned umin32(unsigned a, unsigned b) { return a < b ? a : b; }
__device__ __forceinline__ unsigned umax32(unsigned a, unsigned b) { return a > b ? a : b; }

// monotone float->u32 map; min-u64 over (mapped_s, k) == "lowest s, tie -> lowest k"
// == numpy argmin-first semantics. Order-independent, deterministic.
__device__ __forceinline__ unsigned long long packkey(float s, int k) {
    unsigned b = __float_as_uint(s);
    unsigned m = (b & 0x80000000u) ? ~b : (b | 0x80000000u);
    return ((unsigned long long)m << 32) | (unsigned)k;
}

// ---------- Bq[k] = np.sum(cb_row^2), numpy pairwise tree (verified r2) ----------
__global__ void codesq_kernel(const float* __restrict__ cb, float* __restrict__ Bq) {
#pragma clang fp contract(off)
    int k = blockIdx.x * 256 + threadIdx.x;
    if (k >= KCODES) return;
    const float* er = cb + (size_t)k * CDIM;
    float half_s[2];
    for (int h = 0; h < 2; ++h) {
        float r[8];
        #pragma unroll
        for (int j = 0; j < 8; ++j) { float v = er[h*128 + j]; r[j] = v * v; }
        for (int i = 8; i < 128; i += 8) {
            #pragma unroll
            for (int j = 0; j < 8; ++j) { float v = er[h*128 + i + j]; float sq = v*v; r[j] = r[j] + sq; }
        }
        half_s[h] = ((r[0]+r[1]) + (r[2]+r[3])) + ((r[4]+r[5]) + (r[6]+r[7]));
    }
    Bq[k] = half_s[0] + half_s[1];
}

// ---------- cb fp32 -> bf16 (+ zero flag counter) ----------
__global__ void cbcvt_kernel(const float* __restrict__ cb, unsigned short* __restrict__ cbbf,
                             int* __restrict__ counter) {
    int i = blockIdx.x * 256 + threadIdx.x;      // 65536 float4 groups
    float4 v = ((const float4*)cb)[i];
    ushort4 o;
    o.x = bf16rne(v.x); o.y = bf16rne(v.y); o.z = bf16rne(v.z); o.w = bf16rne(v.w);
    ((ushort4*)cbbf)[i] = o;
    if (i == 0) *counter = 0;
}

// ---------- MFMA bf16 screen: per-row top2 of (|e|^2 - 2 x.e) ----------
// r8: revert r7's (256,4) spill disaster (VGPR 64, 1GB scratch traffic). Back to
// (256,2) and restructure for ILP instead of TLP: per kt, TWO cf passes, each
// batch-issues 8 B-loads into bfr[8] (32 regs, pipelined in flight) before the
// MFMA chain. Per-cf epilogue is order-independent (top-2 of a set). Live state
// ~150 regs -> no spill, and possibly 3 waves/SIMD residency.
__global__ __launch_bounds__(256, 2)
void screen_kernel(const float* __restrict__ x, const unsigned short* __restrict__ cbbf,
                   const float* __restrict__ Bq,
                   int* __restrict__ idx_out, float* __restrict__ outF,
                   int* __restrict__ flag_list, int* __restrict__ counter,
                   unsigned long long* __restrict__ slots) {
    __shared__ unsigned short xs[64 * 264];      // [row][c], pad 256->264 (A operand)
    __shared__ unsigned int sRed[4][64][2];

    const int t = threadIdx.x;
    const int w = t >> 6, l = t & 63;
    const int l15 = l & 15, quad = l >> 4;
    const int r0 = blockIdx.x * 64;
    const float* xbase = x + (size_t)(r0 >> 12) * (CDIM * HWSZ) + (r0 & 4095);

    // ---- stage x tile: fp32 [c][row] global -> bf16 [row][c] LDS (once) ----
    {
        int cbase = (t >> 4) * 2;
        int row4  = (t & 15) * 4;
        for (int it = 0; it < 8; ++it) {
            int c = cbase + it * 32;
            float4 fa = *(const float4*)(xbase + (size_t)c * HWSZ + row4);
            float4 fb = *(const float4*)(xbase + (size_t)(c + 1) * HWSZ + row4);
            *(uint32_t*)&xs[(row4+0)*264 + c] = (uint32_t)bf16rne(fa.x) | ((uint32_t)bf16rne(fb.x) << 16);
            *(uint32_t*)&xs[(row4+1)*264 + c] = (uint32_t)bf16rne(fa.y) | ((uint32_t)bf16rne(fb.y) << 16);
            *(uint32_t*)&xs[(row4+2)*264 + c] = (uint32_t)bf16rne(fa.z) | ((uint32_t)bf16rne(fb.z) << 16);
            *(uint32_t*)&xs[(row4+3)*264 + c] = (uint32_t)bf16rne(fa.w) | ((uint32_t)bf16rne(fb.w) << 16);
        }
    }

    __syncthreads();

    const unsigned short* bbase = cbbf + (size_t)(w*32 + l15) * CDIM + quad * 8;
    const int kbase = w*32 + l15;

    unsigned int K1[16], K2[16];
    #pragma unroll
    for (int i = 0; i < 16; ++i) { K1[i] = 0xFFFFFFFFu; K2[i] = 0xFFFFFFFFu; }

    for (int kt = 0; kt < 8; ++kt) {
        #pragma unroll
        for (int cf = 0; cf < 2; ++cf) {
            // batch-issue 8 B-loads (32 regs in flight -> vmcnt pipelining)
            const unsigned short* bb = bbase + (size_t)(kt*128 + cf*16) * CDIM;
            short8 bfr[8];
            #pragma unroll
            for (int step = 0; step < 8; ++step)
                bfr[step] = *(const short8*)(bb + step * 32);

            float bqp = Bq[kt*128 + kbase + cf*16] + 0.75f;

            f32x4 acc[4];
            #pragma unroll
            for (int rf = 0; rf < 4; ++rf) acc[rf] = (f32x4){0.f, 0.f, 0.f, 0.f};

            #pragma unroll
            for (int step = 0; step < 8; ++step) {   // k-chunk of 32: c = step*32 + quad*8 + j
                #pragma unroll
                for (int rf = 0; rf < 4; ++rf) {
                    short8 af = *(const short8*)&xs[(rf*16 + l15)*264 + step*32 + quad*8];
                    acc[rf] = __builtin_amdgcn_mfma_f32_16x16x32_bf16(af, bfr[step], acc[rf], 0, 0, 0);
                }
            }

            // epilogue for this cf (top-2 insertion is order-independent)
            unsigned int kk = (unsigned)(kt*128 + kbase + cf*16);
            #pragma unroll
            for (int rf = 0; rf < 4; ++rf)
                #pragma unroll
                for (int reg = 0; reg < 4; ++reg) {
                    int st = rf*4 + reg;
                    float s = fmaf(-2.f, acc[rf][reg], bqp);
                    unsigned int key = (__float_as_uint(s) & 0xFFFFFC00u) | kk;
                    unsigned int t1 = umin32(key, K1[st]);
                    unsigned int t2 = umax32(key, K1[st]);
                    K1[st] = t1;
                    K2[st] = umin32(t2, K2[st]);
                }
        }
    }

    #pragma unroll
    for (int st = 0; st < 16; ++st) {
        #pragma unroll
        for (int m = 1; m < 16; m <<= 1) {
            unsigned int o1 = (unsigned int)__shfl_xor((int)K1[st], m, 64);
            unsigned int o2 = (unsigned int)__shfl_xor((int)K2[st], m, 64);
            unsigned int n2 = umin32(umax32(K1[st], o1), umin32(K2[st], o2));
            K1[st] = umin32(K1[st], o1);
            K2[st] = n2;
        }
    }
    if (l15 == 0) {
        #pragma unroll
        for (int rf = 0; rf < 4; ++rf)
            #pragma unroll
            for (int reg = 0; reg < 4; ++reg) {
                int r = rf*16 + quad*4 + reg;
                int st = rf*4 + reg;
                sRed[w][r][0] = K1[st];
                sRed[w][r][1] = K2[st];
            }
    }
    __syncthreads();
    if (t < 64) {
        unsigned int A1 = sRed[0][t][0], A2 = sRed[0][t][1];
        #pragma unroll
        for (int ww = 1; ww < 4; ++ww) {
            unsigned int B1 = sRed[ww][t][0], B2 = sRed[ww][t][1];
            unsigned int n2 = umin32(umax32(A1, B1), umin32(A2, B2));
            A1 = umin32(A1, B1);
            A2 = n2;
        }
        int row = r0 + t;
        int k1i = (int)(A1 & 1023u);
        idx_out[row] = k1i;
        outF[row] = (float)k1i;
        float v1 = __uint_as_float(A1 & 0xFFFFFC00u);
        float v2 = __uint_as_float(A2 & 0xFFFFFC00u);
        if (!(v2 - v1 > DELTA_P)) {               // NaN-safe: garbage -> flagged -> exact path
            int pos = atomicAdd(counter, 1);
            flag_list[pos] = row;
            slots[pos] = 0xFFFFFFFFFFFFFFFFull;   // init argmin slot for rescore
        }
    }
}

// ---------- xcopy: gather flagged rows' exact fp32 x into compact [flag][256] ----------
__global__ __launch_bounds__(256)
void xcopy_kernel(const float* __restrict__ x, const int* __restrict__ flag_list,
                  const int* __restrict__ counter, float* __restrict__ xc, int capn) {
    int cnt = *counter; if (cnt > capn) cnt = capn;
    for (int base = blockIdx.x * 64; base < cnt; base += gridDim.x * 64) {
        int j = base + (threadIdx.x >> 2);
        if (j < cnt) {
            int row = flag_list[j];
            const float* xr = x + (size_t)(row >> 12) * (CDIM * HWSZ) + (row & 4095);
            int c0 = (threadIdx.x & 3) * 64;
            float* dst = xc + (size_t)j * CDIM + c0;
            #pragma unroll 8
            for (int c = 0; c < 64; ++c)
                dst[c] = xr[(size_t)(c0 + c) * HWSZ];
        }
    }
}

// ---------- A[j] = np.sum(x_row^2) for flagged rows, verified numpy pairwise tree ----------
// Reads the exact-copy xc values (or scattered x beyond capn) -> bit-identical to the
// in-rescore sA computation it replaces.
__global__ void asq_kernel(const float* __restrict__ x, const float* __restrict__ xc,
                           const int* __restrict__ flag_list, const int* __restrict__ counter,
                           float* __restrict__ As, int capn) {
#pragma clang fp contract(off)
    int cnt = *counter;
    int jf = blockIdx.x * 256 + threadIdx.x;
    if (jf >= cnt) return;
    const float* src;
    size_t stride;
    if (jf < capn) { src = xc + (size_t)jf * CDIM; stride = 1; }
    else {
        int row = flag_list[jf];
        src = x + (size_t)(row >> 12) * (CDIM * HWSZ) + (row & 4095);
        stride = HWSZ;
    }
    float half_s[2];
    for (int h = 0; h < 2; ++h) {
        float r[8];
        #pragma unroll
        for (int j = 0; j < 8; ++j) { float v = src[(size_t)(h*128 + j) * stride]; r[j] = v * v; }
        for (int i = 8; i < 128; i += 8) {
            #pragma unroll
            for (int j = 0; j < 8; ++j) { float v = src[(size_t)(h*128 + i + j) * stride]; float sq = v*v; r[j] = r[j] + sq; }
        }
        half_s[h] = ((r[0]+r[1]) + (r[2]+r[3])) + ((r[4]+r[5]) + (r[6]+r[7]));
    }
    As[jf] = half_s[0] + half_s[1];
}

// ---------- exact np-fp32 rescore, v5 (unchanged -- out of top-5 at r6) ----------
// Per (row,code): single fp32 fmaf chain c=0..255 ascending; T1=A+Bq; s=T1-2*acc.
__global__ __launch_bounds__(256, 2)
void rescore_kernel(const float* __restrict__ x, const float* __restrict__ cb,
                    const float* __restrict__ Bq,
                    const int* __restrict__ flag_list, const int* __restrict__ counter,
                    const float* __restrict__ xc, const float* __restrict__ As, int capn,
                    unsigned long long* __restrict__ slots) {
    __shared__ float cbs[64 * 256];     // 64 codes, chunk-swizzled: lc -> lc^(code&7)

    int cnt = *counter;
    if (cnt <= 0) return;
    int nbat  = (cnt + 63) >> 6;
    int nwork = nbat << 4;
    for (int wk = blockIdx.x; wk < nwork; wk += gridDim.x) {
        int bat = wk >> 4;
        int kt0 = (wk & 15) << 6;       // this unit's 64-code tile base
        __syncthreads();
        // stage 64 codes coalesced, chunk-swizzled
        {
            int kc = threadIdx.x >> 2, seg = threadIdx.x & 3;
            const float* crow = cb + (size_t)(kt0 + kc) * CDIM + seg * 64;
            float* dst = &cbs[kc * 256];
            int kw = kc & 7;
            #pragma unroll
            for (int i2 = 0; i2 < 16; ++i2) {
                int lc = seg*16 + i2;
                *(float4*)&dst[(lc ^ kw) << 2] = *(const float4*)&crow[i2 << 2];
            }
        }
        __syncthreads();

        const int rq = threadIdx.x >> 4;      // row quad: flag idx j0+0..3
        const int cq = threadIdx.x & 15;      // code lane: codes cq + 16*j, j=0..3
        const int sw = cq & 7;
        const int j0 = bat * 64 + rq * 4;

        int jc[4]; float Ar[4];
        #pragma unroll
        for (int i = 0; i < 4; ++i) {
            int jj = j0 + i;
            jc[i] = (jj < cnt) ? jj : (cnt - 1);
            Ar[i] = As[jc[i]];
        }
        float bq[4]; const float* eb[4];
        #pragma unroll
        for (int j = 0; j < 4; ++j) {
            bq[j] = Bq[kt0 + cq + j*16];
            eb[j] = &cbs[(cq + j*16) * 256];
        }

        float acc[4][4];
        #pragma unroll
        for (int i = 0; i < 4; ++i)
            #pragma unroll
            for (int j = 0; j < 4; ++j) acc[i][j] = 0.f;

        if (jc[3] < capn) {
            // fast path: xv from compact xc (exact copies -> identical chain values)
            const float* xb[4];
            #pragma unroll
            for (int i = 0; i < 4; ++i) xb[i] = xc + (size_t)jc[i] * CDIM;
            #pragma unroll 2
            for (int c4 = 0; c4 < 64; ++c4) {
                float4 ev[4], xv[4];
                #pragma unroll
                for (int j = 0; j < 4; ++j) ev[j] = *(const float4*)&eb[j][(c4 ^ sw) << 2];
                #pragma unroll
                for (int i = 0; i < 4; ++i) xv[i] = *(const float4*)&xb[i][c4 << 2];
                #pragma unroll
                for (int i = 0; i < 4; ++i)
                    #pragma unroll
                    for (int j = 0; j < 4; ++j) {
                        float a = acc[i][j];
                        a = fmaf(xv[i].x, ev[j].x, a);
                        a = fmaf(xv[i].y, ev[j].y, a);
                        a = fmaf(xv[i].z, ev[j].z, a);
                        a = fmaf(xv[i].w, ev[j].w, a);
                        acc[i][j] = a;
                    }
            }
        } else {
            // fallback (workspace too small): xv gathered from x, same chain order
            const float* xb[4];
            #pragma unroll
            for (int i = 0; i < 4; ++i) {
                int row = flag_list[jc[i]];
                xb[i] = x + (size_t)(row >> 12) * (CDIM * HWSZ) + (row & 4095);
            }
            for (int c4 = 0; c4 < 64; ++c4) {
                float4 ev[4], xv[4];
                #pragma unroll
                for (int j = 0; j < 4; ++j) ev[j] = *(const float4*)&eb[j][(c4 ^ sw) << 2];
                #pragma unroll
                for (int i = 0; i < 4; ++i) {
                    xv[i].x = xb[i][(size_t)(c4*4 + 0) * HWSZ];
                    xv[i].y = xb[i][(size_t)(c4*4 + 1) * HWSZ];
                    xv[i].z = xb[i][(size_t)(c4*4 + 2) * HWSZ];
                    xv[i].w = xb[i][(size_t)(c4*4 + 3) * HWSZ];
                }
                #pragma unroll
                for (int i = 0; i < 4; ++i)
                    #pragma unroll
                    for (int j = 0; j < 4; ++j) {
                        float a = acc[i][j];
                        a = fmaf(xv[i].x, ev[j].x, a);
                        a = fmaf(xv[i].y, ev[j].y, a);
                        a = fmaf(xv[i].z, ev[j].z, a);
                        a = fmaf(xv[i].w, ev[j].w, a);
                        acc[i][j] = a;
                    }
            }
        }

        // finish: T1 = A + Bq; s = T1 - 2*acc  (identical ops; k ascending in j)
        float bv[4]; int bk[4];
        #pragma unroll
        for (int i = 0; i < 4; ++i) { bv[i] = 3.4e38f; bk[i] = 0; }
        #pragma unroll
        for (int j = 0; j < 4; ++j) {
            int k = kt0 + cq + j*16;
            #pragma unroll
            for (int i = 0; i < 4; ++i) {
                float T1 = Ar[i] + bq[j];
                float s  = T1 - 2.0f * acc[i][j];
                if (s < bv[i]) { bv[i] = s; bk[i] = k; }
            }
        }
        // reduce across the 16 code-lanes of each row group, then one atomicMin per row
        #pragma unroll
        for (int i = 0; i < 4; ++i) {
            float b = bv[i]; int k = bk[i];
            #pragma unroll
            for (int m = 1; m < 16; m <<= 1) {
                float ov = __shfl_xor(b, m, 64);
                int   ok = __shfl_xor(k, m, 64);
                if (ov < b || (ov == b && ok < k)) { b = ov; k = ok; }
            }
            bv[i] = b; bk[i] = k;
        }
        if (cq == 0) {
            #pragma unroll
            for (int i = 0; i < 4; ++i) {
                int jj = j0 + i;
                if (jj < cnt) atomicMin(&slots[jj], packkey(bv[i], bk[i]));
            }
        }
    }
}

// ---------- fixup: slots -> idx/outF for flagged rows ----------
__global__ void fixup_kernel(const unsigned long long* __restrict__ slots,
                             const int* __restrict__ flag_list,
                             const int* __restrict__ counter,
                             int* __restrict__ idx_out, float* __restrict__ outF) {
    int cnt = *counter;
    int t = blockIdx.x * 256 + threadIdx.x;
    if (t >= cnt) return;
    int row = flag_list[t];
    int k = (int)(unsigned)(slots[t] & 0xFFFFFFFFull);
    idx_out[row] = k;
    outF[row] = (float)k;
}

// ---------- gather codebook rows + NHWC->NCHW transpose (verified r2, unchanged) ----------
__global__ __launch_bounds__(256)
void gather_kernel(const float* __restrict__ cb, const int* __restrict__ idx,
                   float* __restrict__ out) {
    __shared__ int   sIdx[64];
    __shared__ float tile[64 * 129];
    const int t  = threadIdx.x;
    const int bh = blockIdx.x;
    const int b  = bh >> 6, h = bh & 63;

    if (t < 64) {
        int id = idx[bh * 64 + t];
        sIdx[t] = id;
        out[bh * 64 + t] = (float)id;
    }
    __syncthreads();

    float* qout = out + NROWS + (size_t)b * (CDIM * HWSZ) + h * 64;

    for (int c0 = 0; c0 < CDIM; c0 += 128) {
        if (c0) __syncthreads();
        {
            int ww = t >> 2, seg = t & 3;
            const float* crow = cb + (size_t)sIdx[ww] * CDIM + c0;
            #pragma unroll
            for (int jj = 0; jj < 8; ++jj) {
                int f = seg + 4 * jj;
                float4 v = *(const float4*)(crow + 4 * f);
                float* dst = &tile[ww * 129 + 4 * f];
                dst[0] = v.x; dst[1] = v.y; dst[2] = v.z; dst[3] = v.w;
            }
        }
        __syncthreads();
        {
            int g = t >> 4, w4 = (t & 15) * 4;
            #pragma unroll
            for (int it = 0; it < 8; ++it) {
                int cl = it * 16 + g;
                float4 v;
                v.x = tile[(w4 + 0) * 129 + cl];
                v.y = tile[(w4 + 1) * 129 + cl];
                v.z = tile[(w4 + 2) * 129 + cl];
                v.w = tile[(w4 + 3) * 129 + cl];
                *(float4*)(qout + (size_t)(c0 + cl) * HWSZ + w4) = v;
            }
        }
    }
}

extern "C" void kernel_launch(void* const* d_in, const int* in_sizes, int n_in,
                              void* d_out, int out_size, void* d_ws, size_t ws_size,
                              hipStream_t stream) {
    const float* x  = (const float*)d_in[0];
    const float* cb = (const float*)d_in[1];
    char* ws = (char*)d_ws;
    float*              Bq    = (float*)(ws + WS_BQ);
    int*                idxbf = (int*)(ws + WS_IDX);
    unsigned short*     cbbf  = (unsigned short*)(ws + WS_CBBF);
    int*                cnt   = (int*)(ws + WS_CNT);
    int*                list  = (int*)(ws + WS_LIST);
    unsigned long long* slots = (unsigned long long*)(ws + WS_SLOT);
    float*              As    = (float*)(ws + WS_AS);
    float*              xc    = (float*)(ws + WS_XC);
    float*              out   = (float*)d_out;

    // compact-x capacity from whatever workspace we actually got (runtime-guarded)
    int capn = 0;
    if (ws_size > (size_t)WS_XC) {
        size_t avail = (ws_size - (size_t)WS_XC) / (CDIM * sizeof(float));
        capn = (avail > (size_t)NROWS) ? NROWS : (int)avail;
    }

    codesq_kernel<<<KCODES / 256, 256, 0, stream>>>(cb, Bq);
    cbcvt_kernel <<<256, 256, 0, stream>>>(cb, cbbf, cnt);
    screen_kernel<<<NROWS / 64, 256, 0, stream>>>(x, cbbf, Bq, idxbf, out, list, cnt, slots);
    if (capn > 0)
        xcopy_kernel<<<2048, 256, 0, stream>>>(x, list, cnt, xc, capn);
    asq_kernel   <<<NROWS / 256, 256, 0, stream>>>(x, xc, list, cnt, As, capn);
    rescore_kernel<<<2048, 256, 0, stream>>>(x, cb, Bq, list, cnt, xc, As, capn, slots);
    fixup_kernel <<<NROWS / 256, 256, 0, stream>>>(slots, list, cnt, idxbf, out);
    gather_kernel<<<32 * 64, 256, 0, stream>>>(cb, idxbf, out);
}